// Round 10
// baseline (734.802 us; speedup 1.0000x reference)
//
#include <hip/hip_runtime.h>
#include <math.h>

#define BATCH 16
#define CIN   3
#define HH    224
#define WW    224
#define HW    (HH*WW)
#define COUT  128
#define TAPS  147
#define CAND  192
#define TK    192

typedef __attribute__((ext_vector_type(8))) _Float16 f16x8_t;
typedef decltype(__builtin_amdgcn_cvt_pkrtz(0.f, 0.f)) f16x2_t;
typedef __attribute__((ext_vector_type(4))) float f32x4_t;
typedef __attribute__((ext_vector_type(4))) unsigned int u32x4_t;
typedef unsigned long long u64;
typedef unsigned int u32;

// W layout (global, L2-resident): [g 24][129 chunks of (ch,kw)] f16x8 chunks
#define B_CHUNKS  (24*129)
#define B_BYTES   (B_CHUNKS*16u)      // 49536
#define CPY_STRIDE 2144
#define CPY_BYTES  (8*CPY_STRIDE)     // 17152
#define LDS_CONV  (CPY_BYTES + 512 + 1024)   // 18688

// workspace layout (bytes)
#define WS_BG    0u
#define WS_BSH   (WS_BG + B_BYTES)                       // 512
#define WS_TOP1  (WS_BSH + 512u)                         // 3211264
#define WS_CIDX  (WS_TOP1 + (unsigned)(BATCH*HW*4))      // 12288
#define WS_CKEY  (WS_CIDX + (unsigned)(BATCH*CAND*4))    // 24576
#define WS_C3V   (WS_CKEY + (unsigned)(BATCH*CAND*8))    // 9216
#define WS_C3I   (WS_C3V + (unsigned)(BATCH*CAND*3*4))   // 9216
#define WS_WT    (WS_C3I + (unsigned)(BATCH*CAND*3*4))   // 75264
#define WS_HIST  (WS_WT + (unsigned)(TAPS*COUT*4))       // 65536 (16 x 1024 u32)
#define ZERO_N   (BATCH*1024)

// ---- prep: zero histogram + fp16 folded weights + raw tap-major wT + BN shift ----
__global__ void prep_kernel(const float* __restrict__ w, const float* __restrict__ cb,
                            const float* __restrict__ gamma, const float* __restrict__ beta,
                            const float* __restrict__ mean, const float* __restrict__ var,
                            unsigned short* __restrict__ Bg, float* __restrict__ bsh,
                            float* __restrict__ wT, u32* __restrict__ gh) {
  int c = blockIdx.x;                 // 128
  int t = threadIdx.x;                // 192: g = t>>3 (0..23), kw = t&7
  int zi = c*192 + t;
  if (zi < ZERO_N) gh[zi] = 0u;
  float s = gamma[c] * (1.0f / sqrtf(var[c] + 1e-5f));
  int g = t >> 3, kw = t & 7;
  float wraw = 0.0f;
  if (g < 21 && kw < 7) {
    wraw = w[c*TAPS + g*7 + kw];
    wT[(g*7 + kw)*COUT + c] = wraw;
  }
  union { _Float16 h; unsigned short u; } cvt;
  cvt.h = (_Float16)(wraw * s);
  Bg[((g*129 + c)*8) + kw] = cvt.u;
  if (t == 0) bsh[c] = (cb[c] - mean[c]) * s + beta[c];
}

// ---- main pass: fp16 MFMA conv+BN+ReLU -> per-pixel channel max + coarse histogram ----
// operand-swapped: A=W (D rows = channels, read direct from L2), B=x (cols = pixels, LDS).
__global__ __launch_bounds__(512, 4)
void conv_mfma_kernel(const float* __restrict__ x, const unsigned short* __restrict__ Bg,
                      const float* __restrict__ bsh, float* __restrict__ top1,
                      u32* __restrict__ gh) {
  extern __shared__ char smem[];
  char* xcop = smem;
  float* lbsh = (float*)(smem + CPY_BYTES);
  float* pmax = (float*)(smem + CPY_BYTES + 512);

  int tid = threadIdx.x;
  int lane = tid & 63, wv = tid >> 6;
  int l15 = lane & 15, l4 = lane >> 4;
  int q = wv >> 1, chh = wv & 1;
  int b = blockIdx.z, w0 = blockIdx.x*16, h0 = blockIdx.y*16;
  const float* xb = x + (size_t)b * CIN * HW;

  // stage x as 8 shifted fp16 copies (1056 16B chunks)
  for (int c = tid; c < 8*132; c += 512) {
    int s   = c / 132;
    int rem = c % 132;
    int cin = rem / 44;
    int rm2 = rem % 44;
    int r   = rm2 >> 1, cj = rm2 & 1;
    int gh2 = h0 + r - 3;
    int gwb = w0 - 3 + 8*cj + s;
    const float* xr = xb + cin*HW + gh2*WW;
    bool rowok = (gh2 >= 0 && gh2 < HH);
    float xv[8];
#pragma unroll
    for (int j = 0; j < 8; ++j) {
      int gw = gwb + j;
      xv[j] = (rowok && gw >= 0 && gw < WW) ? xr[gw] : 0.0f;
    }
    union { f16x2_t p[4]; u32x4_t v; } P;
#pragma unroll
    for (int j = 0; j < 4; ++j)
      P.p[j] = __builtin_amdgcn_cvt_pkrtz(xv[2*j], xv[2*j+1]);
    *(u32x4_t*)(xcop + s*CPY_STRIDE + (cin*22 + r)*32 + cj*16) = P.v;
  }
  if (tid < COUT) lbsh[tid] = bsh[tid];

  __syncthreads();

  f32x4_t acc[4][4];
#pragma unroll
  for (int m = 0; m < 4; ++m)
#pragma unroll
    for (int n = 0; n < 4; ++n) acc[m][n] = (f32x4_t){0.f,0.f,0.f,0.f};

  const f16x8_t* Wg = (const f16x8_t*)Bg;     // global (L1/L2-hot)
  int lane_base = (l15 & 7)*CPY_STRIDE + (l15 >> 3)*16;
  const char* xl = xcop + lane_base;

#pragma unroll
  for (int kf = 0; kf < 6; ++kf) {
    f16x8_t Wn[4];
#pragma unroll
    for (int n = 0; n < 4; ++n)
      Wn[n] = Wg[(kf*4 + l4)*129 + chh*64 + n*16 + l15];
    int g = kf*4 + l4;
    int cin = (g*37) >> 8;
    int kh = g - cin*7;
    int rowb = (g < 21) ? (cin*22 + kh + q*4) : 0;   // pads clamped (W=0 there)
#pragma unroll
    for (int m = 0; m < 4; ++m) {
      f16x8_t Av = *(const f16x8_t*)(xl + (rowb + m)*32);
#pragma unroll
      for (int n = 0; n < 4; ++n)
        acc[m][n] = __builtin_amdgcn_mfma_f32_16x16x32_f16(Wn[n], Av, acc[m][n], 0, 0, 0);
    }
  }

  // epilogue: +bias (lane-local), 15 in-lane fmax + 2 shuffles, 1-barrier chh combine
  f32x4_t bv[4];
#pragma unroll
  for (int n = 0; n < 4; ++n)
    bv[n] = *(const f32x4_t*)(lbsh + chh*64 + n*16 + l4*4);
  float vm[4];
#pragma unroll
  for (int m = 0; m < 4; ++m) {
    float v = -1e30f;
#pragma unroll
    for (int n = 0; n < 4; ++n)
#pragma unroll
      for (int r = 0; r < 4; ++r) v = fmaxf(v, acc[m][n][r] + bv[n][r]);
    v = fmaxf(v, __shfl_xor(v, 16));
    v = fmaxf(v, __shfl_xor(v, 32));
    vm[m] = v;
  }
  if (chh == 0 && l4 == 0) {
#pragma unroll
    for (int m = 0; m < 4; ++m) pmax[(q*4 + m)*16 + l15] = vm[m];
  }
  __syncthreads();
  if (chh == 1 && l4 == 0) {
#pragma unroll
    for (int m = 0; m < 4; ++m) {
      float r = fmaxf(fmaxf(vm[m], pmax[(q*4 + m)*16 + l15]), 0.0f);
      top1[(size_t)b*HW + (h0 + q*4 + m)*WW + (w0 + l15)] = r;
      atomicAdd(&gh[b*1024 + (__float_as_uint(r) >> 21)], 1u);   // coarse hist, in-register
    }
  }
}

// ---- select: scan hist -> (conditional fine pass) -> compact -> sort, one kernel ----
#define SNT 1024
__global__ void select_kernel(const float* __restrict__ top1, const u32* __restrict__ gh,
                              int* __restrict__ cand) {
  int img = blockIdx.x, tid = threadIdx.x;   // 1024 threads
  const float* v = top1 + (size_t)img * HW;
  const float4* v4 = (const float4*)v;
  __shared__ u32 lh[1024];
  __shared__ u64 keys[1024];
  __shared__ unsigned sG, scnt, sbin, sthr, snc;

  if (tid < 64) {                            // coarse scan from conv-built histogram
    int j = tid;
    const u32* h = gh + img*1024;
    unsigned s = 0;
#pragma unroll
    for (int i = 0; i < 16; ++i) s += h[j*16 + i];
    unsigned a = s;
#pragma unroll
    for (int d = 1; d < 64; d <<= 1) { unsigned t = __shfl_down(a, d); if (j + d < 64) a += t; }
    unsigned above = a - s;
    if (above < TK && a >= TK) {
      unsigned cum = above;
      for (int i = 15; i >= 0; --i) {
        unsigned c = h[j*16 + i];
        if (cum + c >= TK) { sG = cum; scnt = c; sbin = (unsigned)(j*16 + i); break; }
        cum += c;
      }
    }
    if (j == 0 && a < TK) { sG = 0; scnt = h[0]; sbin = 0; }
  }
  __syncthreads();
  unsigned G = sG, cnt = scnt, binT = sbin;
  unsigned thr = binT << 21;
  if (G + cnt > 1024u) {                     // fine pass (bits 20..11)
    lh[tid] = 0u;
    __syncthreads();
    for (int i = tid; i < HW/4; i += SNT) {
      float4 f = v4[i];
      float fv[4] = {f.x, f.y, f.z, f.w};
#pragma unroll
      for (int c = 0; c < 4; ++c) {
        unsigned ub = __float_as_uint(fv[c]);
        if ((ub >> 21) == binT) atomicAdd(&lh[(ub >> 11) & 0x3FFu], 1u);
      }
    }
    __syncthreads();
    unsigned TK2 = TK - G;
    if (tid < 64) {
      int j = tid;
      unsigned s = 0;
#pragma unroll
      for (int i = 0; i < 16; ++i) s += lh[j*16 + i];
      unsigned a = s;
#pragma unroll
      for (int d = 1; d < 64; d <<= 1) { unsigned t = __shfl_down(a, d); if (j + d < 64) a += t; }
      unsigned above = a - s;
      if (above < TK2 && a >= TK2) {
        unsigned cum = above;
        for (int i = 15; i >= 0; --i) {
          unsigned c = lh[j*16 + i];
          if (cum + c >= TK2) { sthr = (binT << 21) | ((unsigned)(j*16 + i) << 11); break; }
          cum += c;
        }
      }
      if (j == 0 && a < TK2) sthr = binT << 21;
    }
    __syncthreads();
    thr = sthr;
  }
  if (tid == 0) snc = 0u;
  keys[tid] = 0ull;
  __syncthreads();
  for (int i = tid; i < HW/4; i += SNT) {
    float4 f = v4[i];
    float fv[4] = {f.x, f.y, f.z, f.w};
#pragma unroll
    for (int c = 0; c < 4; ++c) {
      unsigned ub = __float_as_uint(fv[c]);
      if (ub >= thr) {
        unsigned p = atomicAdd(&snc, 1u);
        if (p < 1024u) keys[p] = ((u64)ub << 32) | (unsigned)(~(unsigned)(4*i + c));
      }
    }
  }
  for (unsigned kk = 2; kk <= 1024; kk <<= 1)
    for (unsigned j = kk >> 1; j > 0; j >>= 1) {
      __syncthreads();
      unsigned t = tid, ixj = t ^ j;
      if (ixj > t) {
        u64 a = keys[t], b = keys[ixj];
        bool desc = ((t & kk) == 0);
        if ((a < b) == desc) { keys[t] = b; keys[ixj] = a; }
      }
    }
  __syncthreads();
  if (tid < CAND) {
    u64 key = keys[tid];
    cand[img*CAND + tid] = (key == 0ull) ? -1 : (int)(~(unsigned)(key & 0xFFFFFFFFull));
  }
}

// ---- fp64 recompute at candidates (coalesced wT, LDS x-patch, parallel top3) ----
__global__ void refine_kernel(const float* __restrict__ x, const float* __restrict__ wT,
                              const float* __restrict__ cb, const float* __restrict__ gamma,
                              const float* __restrict__ beta, const float* __restrict__ mean,
                              const float* __restrict__ var, const int* __restrict__ cand,
                              u64* __restrict__ ckey,
                              float* __restrict__ c3v, float* __restrict__ c3i) {
#pragma clang fp contract(off)
  int slot = blockIdx.x, img = blockIdx.y;
  int c = threadIdx.x;                       // 128 threads = channels
  int sidx = cand[img*CAND + slot];
  if (sidx < 0) {
    if (c == 0) {
      ckey[img*CAND + slot] = 0ull;
      for (int j = 0; j < 3; ++j) { c3v[(img*CAND+slot)*3+j] = 0.f; c3i[(img*CAND+slot)*3+j] = 0.f; }
    }
    return;
  }
  int h = sidx / WW, wq = sidx % WW;
  const float* xb = x + (size_t)img * CIN * HW;

  __shared__ float xs[TAPS + 13];
  for (int t = c; t < TAPS; t += 128) {
    int cin = t / 49, r = t % 49;
    int kh = r / 7, kw = r % 7;
    int gh = h - 3 + kh, gw = wq - 3 + kw;
    float v = 0.0f;
    if (gh >= 0 && gh < HH && gw >= 0 && gw < WW) v = xb[cin*HW + gh*WW + gw];
    xs[t] = v;
  }
  __syncthreads();

  double acc = 0.0;
#pragma unroll 7
  for (int t = 0; t < TAPS; ++t)
    acc = fma((double)xs[t], (double)wT[t*COUT + c], acc);

  float y = (float)acc;
  y = y + cb[c];
  float s  = gamma[c] * (1.0f / sqrtf(var[c] + 1e-5f));
  float t1 = (y - mean[c]) * s;
  float z  = t1 + beta[c];
  z = fmaxf(z, 0.0f);

  __shared__ u64 zk[COUT];
  zk[c] = ((u64)__float_as_uint(z) << 32) | (unsigned)(127 - c);
  __syncthreads();
  if (c < 64) {
    u64 k0 = zk[c], k1 = zk[c + 64];
    int base = (img*CAND + slot)*3;
#pragma unroll
    for (int pick = 0; pick < 3; ++pick) {
      u64 m = (k0 > k1) ? k0 : k1;
#pragma unroll
      for (int d = 1; d < 64; d <<= 1) {
        u64 o = __shfl_xor((unsigned long long)m, d);
        if (o > m) m = o;
      }
      if (c == 0) {
        float vv = __uint_as_float((unsigned)(m >> 32));
        int ch = 127 - (int)(m & 0xFFFFFFFFull);
        c3v[base + pick] = vv;
        c3i[base + pick] = (float)ch;
        if (pick == 0)
          ckey[img*CAND + slot] = ((u64)(m >> 32) << 32) | (unsigned)(~(unsigned)sidx);
      }
      if (k0 == m) k0 = 0ull;
      if (k1 == m) k1 = 0ull;
    }
  }
}

// ---- final: sort 192 refined candidates, write all three outputs ----
__global__ void final_kernel(const u64* __restrict__ ckey, const int* __restrict__ cand,
                             const float* __restrict__ c3v, const float* __restrict__ c3i,
                             float* __restrict__ out) {
  int img = blockIdx.x, tid = threadIdx.x;   // 256 threads
  __shared__ u64 k[256];
  __shared__ int pay[256];
  k[tid]  = (tid < CAND) ? ckey[img*CAND + tid] : 0ull;
  pay[tid] = tid;
  for (unsigned kk = 2; kk <= 256; kk <<= 1)
    for (unsigned j = kk >> 1; j > 0; j >>= 1) {
      __syncthreads();
      unsigned i = tid, ixj = i ^ j;
      if (ixj > i) {
        u64 a = k[i], b = k[ixj];
        bool desc = ((i & kk) == 0);
        if ((a < b) == desc) {
          k[i] = b; k[ixj] = a;
          int p = pay[i]; pay[i] = pay[ixj]; pay[ixj] = p;
        }
      }
    }
  __syncthreads();
  if (tid < 128) {
    int slot = pay[tid];
    int sidx = cand[img*CAND + slot];
    out[12288 + img*128 + tid] = (float)sidx;
    int base = (img*CAND + slot)*3;
    for (int j = 0; j < 3; ++j) {
      out[(img*3 + j)*128 + tid]        = c3i[base + j];
      out[6144 + (img*3 + j)*128 + tid] = c3v[base + j];
    }
  }
}

extern "C" void kernel_launch(void* const* d_in, const int* in_sizes, int n_in,
                              void* d_out, int out_size, void* d_ws, size_t ws_size,
                              hipStream_t stream) {
  const float* x     = (const float*)d_in[0];
  const float* w     = (const float*)d_in[1];
  const float* cb    = (const float*)d_in[2];
  const float* gamma = (const float*)d_in[3];
  const float* beta  = (const float*)d_in[4];
  const float* mean  = (const float*)d_in[5];
  const float* var   = (const float*)d_in[6];
  float* out = (float*)d_out;
  char*  ws  = (char*)d_ws;

  unsigned short* Bg = (unsigned short*)(ws + WS_BG);
  float* bsh  = (float*)(ws + WS_BSH);
  float* top1 = (float*)(ws + WS_TOP1);
  int*   cidx = (int*)(ws + WS_CIDX);
  u64*   ck   = (u64*)(ws + WS_CKEY);
  float* c3v = (float*)(ws + WS_C3V);
  float* c3i = (float*)(ws + WS_C3I);
  float* wT  = (float*)(ws + WS_WT);
  u32* gh    = (u32*)(ws + WS_HIST);

  prep_kernel<<<COUT, 192, 0, stream>>>(w, cb, gamma, beta, mean, var, Bg, bsh, wT, gh);
  conv_mfma_kernel<<<dim3(WW/16, HH/16, BATCH), 512, LDS_CONV, stream>>>(x, Bg, bsh, top1, gh);
  select_kernel<<<BATCH, SNT, 0, stream>>>(top1, gh, cidx);
  refine_kernel<<<dim3(CAND, BATCH), COUT, 0, stream>>>(x, wT, cb, gamma, beta, mean, var,
                                                        cidx, ck, c3v, c3i);
  final_kernel<<<BATCH, 256, 0, stream>>>(ck, cidx, c3v, c3i, out);
}

// Round 11
// 117.759 us; speedup vs baseline: 6.2399x; 6.2399x over previous
//
#include <hip/hip_runtime.h>
#include <math.h>

#define BATCH 16
#define CIN   3
#define HH    224
#define WW    224
#define HW    (HH*WW)
#define COUT  128
#define TAPS  147
#define CAND  192
#define TK    192

typedef __attribute__((ext_vector_type(8))) _Float16 f16x8_t;
typedef decltype(__builtin_amdgcn_cvt_pkrtz(0.f, 0.f)) f16x2_t;
typedef __attribute__((ext_vector_type(4))) float f32x4_t;
typedef __attribute__((ext_vector_type(4))) unsigned int u32x4_t;
typedef unsigned long long u64;
typedef unsigned int u32;

// W layout: [g 24][129 chunks of (ch,kw)] f16x8 chunks; oct stride 129 chunks (bank-skewed)
#define B_CHUNKS  (24*129)
#define B_BYTES   (B_CHUNKS*16u)      // 49536
#define CPY_STRIDE 2144
#define CPY_BYTES  (8*CPY_STRIDE)     // 17152
#define LDS_CONV  (B_BYTES + CPY_BYTES + 512 + 1024)   // 68224

// workspace layout (bytes)
#define WS_BG    0u
#define WS_BSH   (WS_BG + B_BYTES)
#define WS_TOP1  (WS_BSH + 512u)
#define WS_CIDX  (WS_TOP1 + (unsigned)(BATCH*HW*4))
#define WS_CKEY  (WS_CIDX + (unsigned)(BATCH*CAND*4))
#define WS_C3V   (WS_CKEY + (unsigned)(BATCH*CAND*8))
#define WS_C3I   (WS_C3V + (unsigned)(BATCH*CAND*3*4))
#define WS_WT    (WS_C3I + (unsigned)(BATCH*CAND*3*4))

__device__ __forceinline__ void gload_lds16(const u32* g, u32* l) {
  __builtin_amdgcn_global_load_lds((const __attribute__((address_space(1))) u32*)g,
                                   (__attribute__((address_space(3))) u32*)l, 16, 0, 0);
}

// ---- prep: fp16 folded weights (skewed layout) + raw tap-major wT + BN shift ----
__global__ void prep_kernel(const float* __restrict__ w, const float* __restrict__ cb,
                            const float* __restrict__ gamma, const float* __restrict__ beta,
                            const float* __restrict__ mean, const float* __restrict__ var,
                            unsigned short* __restrict__ Bg, float* __restrict__ bsh,
                            float* __restrict__ wT) {
  int c = blockIdx.x;                 // 128
  int t = threadIdx.x;                // 192: g = t>>3 (0..23), kw = t&7
  float s = gamma[c] * (1.0f / sqrtf(var[c] + 1e-5f));
  int g = t >> 3, kw = t & 7;
  float wraw = 0.0f;
  if (g < 21 && kw < 7) {
    wraw = w[c*TAPS + g*7 + kw];
    wT[(g*7 + kw)*COUT + c] = wraw;
  }
  union { _Float16 h; unsigned short u; } cvt;
  cvt.h = (_Float16)(wraw * s);
  Bg[((g*129 + c)*8) + kw] = cvt.u;
  if (t == 0) bsh[c] = (cb[c] - mean[c]) * s + beta[c];
}

// ---- main pass: fp16 MFMA conv+BN+ReLU -> per-pixel channel max ----
// operand-swapped: A=W (D rows = channels), B=x (D cols = pixels). W staged in LDS.
__global__ __launch_bounds__(512, 4)
void conv_mfma_kernel(const float* __restrict__ x, const unsigned short* __restrict__ Bg,
                      const float* __restrict__ bsh, float* __restrict__ top1) {
  extern __shared__ char smem[];
  char* xcop = smem + B_BYTES;
  float* lbsh = (float*)(smem + B_BYTES + CPY_BYTES);
  float* pmax = (float*)(smem + B_BYTES + CPY_BYTES + 512);

  int tid = threadIdx.x;
  int lane = tid & 63, wv = tid >> 6;
  int l15 = lane & 15, l4 = lane >> 4;
  int q = wv >> 1, chh = wv & 1;
  int b = blockIdx.z, w0 = blockIdx.x*16, h0 = blockIdx.y*16;
  const float* xb = x + (size_t)b * CIN * HW;
  const u32* Bg32 = (const u32*)Bg;

  // stage W (async, 16B chunks)
#pragma unroll
  for (int k = 0; k < 7; ++k) {
    int idx = tid + k*512;
    if (idx < B_CHUNKS) gload_lds16(Bg32 + idx*4, (u32*)smem + idx*4);
  }
  // stage x as 8 shifted fp16 copies
  for (int c = tid; c < 8*132; c += 512) {
    int s   = c / 132;
    int rem = c % 132;
    int cin = rem / 44;
    int rm2 = rem % 44;
    int r   = rm2 >> 1, cj = rm2 & 1;
    int gh = h0 + r - 3;
    int gwb = w0 - 3 + 8*cj + s;
    const float* xr = xb + cin*HW + gh*WW;
    bool rowok = (gh >= 0 && gh < HH);
    float xv[8];
#pragma unroll
    for (int j = 0; j < 8; ++j) {
      int gw = gwb + j;
      xv[j] = (rowok && gw >= 0 && gw < WW) ? xr[gw] : 0.0f;
    }
    union { f16x2_t p[4]; u32x4_t v; } P;
#pragma unroll
    for (int j = 0; j < 4; ++j)
      P.p[j] = __builtin_amdgcn_cvt_pkrtz(xv[2*j], xv[2*j+1]);
    *(u32x4_t*)(xcop + s*CPY_STRIDE + (cin*22 + r)*32 + cj*16) = P.v;
  }
  if (tid < COUT) lbsh[tid] = bsh[tid];

  __syncthreads();

  f32x4_t acc[4][4];
#pragma unroll
  for (int m = 0; m < 4; ++m)
#pragma unroll
    for (int n = 0; n < 4; ++n) acc[m][n] = (f32x4_t){0.f,0.f,0.f,0.f};

  const f16x8_t* B8 = (const f16x8_t*)smem;
  int lane_base = (l15 & 7)*CPY_STRIDE + (l15 >> 3)*16;
  const char* xl = xcop + lane_base;

#pragma unroll
  for (int kf = 0; kf < 6; ++kf) {
    f16x8_t Wn[4];
#pragma unroll
    for (int n = 0; n < 4; ++n)
      Wn[n] = B8[(kf*4 + l4)*129 + chh*64 + n*16 + l15];
    int g = kf*4 + l4;
    int cin = (g*37) >> 8;
    int kh = g - cin*7;
    int rowb = (g < 21) ? (cin*22 + kh + q*4) : 0;   // pads clamped (W=0 there)
#pragma unroll
    for (int m = 0; m < 4; ++m) {
      f16x8_t Av = *(const f16x8_t*)(xl + (rowb + m)*32);
#pragma unroll
      for (int n = 0; n < 4; ++n)
        acc[m][n] = __builtin_amdgcn_mfma_f32_16x16x32_f16(Wn[n], Av, acc[m][n], 0, 0, 0);
    }
  }

  // epilogue: +bias (lane-local), 15 in-lane fmax + 2 shuffles, 1-barrier chh combine
  f32x4_t bv[4];
#pragma unroll
  for (int n = 0; n < 4; ++n)
    bv[n] = *(const f32x4_t*)(lbsh + chh*64 + n*16 + l4*4);
  float vm[4];
#pragma unroll
  for (int m = 0; m < 4; ++m) {
    float v = -1e30f;
#pragma unroll
    for (int n = 0; n < 4; ++n)
#pragma unroll
      for (int r = 0; r < 4; ++r) v = fmaxf(v, acc[m][n][r] + bv[n][r]);
    v = fmaxf(v, __shfl_xor(v, 16));
    v = fmaxf(v, __shfl_xor(v, 32));
    vm[m] = v;
  }
  if (chh == 0 && l4 == 0) {
#pragma unroll
    for (int m = 0; m < 4; ++m) pmax[(q*4 + m)*16 + l15] = vm[m];
  }
  __syncthreads();
  if (chh == 1 && l4 == 0) {
#pragma unroll
    for (int m = 0; m < 4; ++m) {
      float r = fmaxf(fmaxf(vm[m], pmax[(q*4 + m)*16 + l15]), 0.0f);
      top1[(size_t)b*HW + (h0 + q*4 + m)*WW + (w0 + l15)] = r;
    }
  }
}

// ---- select: LDS hist -> scan -> (conditional fine pass) -> compact -> sort ----
#define SNT 1024
__global__ void select_kernel(const float* __restrict__ top1, int* __restrict__ cand) {
  int img = blockIdx.x, tid = threadIdx.x;   // 1024 threads
  const float* v = top1 + (size_t)img * HW;
  const float4* v4 = (const float4*)v;
  __shared__ u32 hist[1024];
  __shared__ u64 keys[1024];
  __shared__ unsigned sG, scnt, sbin, sthr, snc;

  hist[tid] = 0u;
  __syncthreads();
  for (int i = tid; i < HW/4; i += SNT) {
    float4 f = v4[i];
    atomicAdd(&hist[__float_as_uint(f.x) >> 21], 1u);
    atomicAdd(&hist[__float_as_uint(f.y) >> 21], 1u);
    atomicAdd(&hist[__float_as_uint(f.z) >> 21], 1u);
    atomicAdd(&hist[__float_as_uint(f.w) >> 21], 1u);
  }
  __syncthreads();
  if (tid < 64) {
    int j = tid;
    unsigned s = 0;
#pragma unroll
    for (int i = 0; i < 16; ++i) s += hist[j*16 + i];
    unsigned a = s;
#pragma unroll
    for (int d = 1; d < 64; d <<= 1) { unsigned t = __shfl_down(a, d); if (j + d < 64) a += t; }
    unsigned above = a - s;
    if (above < TK && a >= TK) {
      unsigned cum = above;
      for (int i = 15; i >= 0; --i) {
        unsigned c = hist[j*16 + i];
        if (cum + c >= TK) { sG = cum; scnt = c; sbin = (unsigned)(j*16 + i); break; }
        cum += c;
      }
    }
    if (j == 0 && a < TK) { sG = 0; scnt = hist[0]; sbin = 0; }
  }
  __syncthreads();
  unsigned G = sG, cnt = scnt, binT = sbin;
  unsigned thr = binT << 21;
  if (G + cnt > 1024u) {
    __syncthreads();
    hist[tid] = 0u;
    __syncthreads();
    for (int i = tid; i < HW/4; i += SNT) {
      float4 f = v4[i];
      float fv[4] = {f.x, f.y, f.z, f.w};
#pragma unroll
      for (int c = 0; c < 4; ++c) {
        unsigned ub = __float_as_uint(fv[c]);
        if ((ub >> 21) == binT) atomicAdd(&hist[(ub >> 11) & 0x3FFu], 1u);
      }
    }
    __syncthreads();
    unsigned TK2 = TK - G;
    if (tid < 64) {
      int j = tid;
      unsigned s = 0;
#pragma unroll
      for (int i = 0; i < 16; ++i) s += hist[j*16 + i];
      unsigned a = s;
#pragma unroll
      for (int d = 1; d < 64; d <<= 1) { unsigned t = __shfl_down(a, d); if (j + d < 64) a += t; }
      unsigned above = a - s;
      if (above < TK2 && a >= TK2) {
        unsigned cum = above;
        for (int i = 15; i >= 0; --i) {
          unsigned c = hist[j*16 + i];
          if (cum + c >= TK2) { sthr = (binT << 21) | ((unsigned)(j*16 + i) << 11); break; }
          cum += c;
        }
      }
      if (j == 0 && a < TK2) sthr = binT << 21;
    }
    __syncthreads();
    thr = sthr;
  }
  if (tid == 0) snc = 0u;
  keys[tid] = 0ull;
  __syncthreads();
  for (int i = tid; i < HW/4; i += SNT) {
    float4 f = v4[i];
    float fv[4] = {f.x, f.y, f.z, f.w};
#pragma unroll
    for (int c = 0; c < 4; ++c) {
      unsigned ub = __float_as_uint(fv[c]);
      if (ub >= thr) {
        unsigned p = atomicAdd(&snc, 1u);
        if (p < 1024u) keys[p] = ((u64)ub << 32) | (unsigned)(~(unsigned)(4*i + c));
      }
    }
  }
  for (unsigned kk = 2; kk <= 1024; kk <<= 1)
    for (unsigned j = kk >> 1; j > 0; j >>= 1) {
      __syncthreads();
      unsigned t = tid, ixj = t ^ j;
      if (ixj > t) {
        u64 a = keys[t], b = keys[ixj];
        bool desc = ((t & kk) == 0);
        if ((a < b) == desc) { keys[t] = b; keys[ixj] = a; }
      }
    }
  __syncthreads();
  if (tid < CAND) {
    u64 key = keys[tid];
    cand[img*CAND + tid] = (key == 0ull) ? -1 : (int)(~(unsigned)(key & 0xFFFFFFFFull));
  }
}

// ---- fp64 recompute at candidates (coalesced wT, LDS x-patch, parallel top3) ----
__global__ void refine_kernel(const float* __restrict__ x, const float* __restrict__ wT,
                              const float* __restrict__ cb, const float* __restrict__ gamma,
                              const float* __restrict__ beta, const float* __restrict__ mean,
                              const float* __restrict__ var, const int* __restrict__ cand,
                              u64* __restrict__ ckey,
                              float* __restrict__ c3v, float* __restrict__ c3i) {
#pragma clang fp contract(off)
  int slot = blockIdx.x, img = blockIdx.y;
  int c = threadIdx.x;                       // 128 threads = channels
  int sidx = cand[img*CAND + slot];
  if (sidx < 0) {
    if (c == 0) {
      ckey[img*CAND + slot] = 0ull;
      for (int j = 0; j < 3; ++j) { c3v[(img*CAND+slot)*3+j] = 0.f; c3i[(img*CAND+slot)*3+j] = 0.f; }
    }
    return;
  }
  int h = sidx / WW, wq = sidx % WW;
  const float* xb = x + (size_t)img * CIN * HW;

  __shared__ float xs[TAPS + 13];
  for (int t = c; t < TAPS; t += 128) {
    int cin = t / 49, r = t % 49;
    int kh = r / 7, kw = r % 7;
    int gh = h - 3 + kh, gw = wq - 3 + kw;
    float v = 0.0f;
    if (gh >= 0 && gh < HH && gw >= 0 && gw < WW) v = xb[cin*HW + gh*WW + gw];
    xs[t] = v;
  }
  __syncthreads();

  double acc = 0.0;
#pragma unroll 7
  for (int t = 0; t < TAPS; ++t)
    acc = fma((double)xs[t], (double)wT[t*COUT + c], acc);

  float y = (float)acc;
  y = y + cb[c];
  float s  = gamma[c] * (1.0f / sqrtf(var[c] + 1e-5f));
  float t1 = (y - mean[c]) * s;
  float z  = t1 + beta[c];
  z = fmaxf(z, 0.0f);

  __shared__ u64 zk[COUT];
  zk[c] = ((u64)__float_as_uint(z) << 32) | (unsigned)(127 - c);
  __syncthreads();
  if (c < 64) {
    u64 k0 = zk[c], k1 = zk[c + 64];
    int base = (img*CAND + slot)*3;
#pragma unroll
    for (int pick = 0; pick < 3; ++pick) {
      u64 m = (k0 > k1) ? k0 : k1;
#pragma unroll
      for (int d = 1; d < 64; d <<= 1) {
        u64 o = __shfl_xor((unsigned long long)m, d);
        if (o > m) m = o;
      }
      if (c == 0) {
        float vv = __uint_as_float((unsigned)(m >> 32));
        int ch = 127 - (int)(m & 0xFFFFFFFFull);
        c3v[base + pick] = vv;
        c3i[base + pick] = (float)ch;
        if (pick == 0)
          ckey[img*CAND + slot] = ((u64)(m >> 32) << 32) | (unsigned)(~(unsigned)sidx);
      }
      if (k0 == m) k0 = 0ull;
      if (k1 == m) k1 = 0ull;
    }
  }
}

// ---- final: sort 192 refined candidates, write all three outputs ----
__global__ void final_kernel(const u64* __restrict__ ckey, const int* __restrict__ cand,
                             const float* __restrict__ c3v, const float* __restrict__ c3i,
                             float* __restrict__ out) {
  int img = blockIdx.x, tid = threadIdx.x;   // 256 threads
  __shared__ u64 k[256];
  __shared__ int pay[256];
  k[tid]  = (tid < CAND) ? ckey[img*CAND + tid] : 0ull;
  pay[tid] = tid;
  for (unsigned kk = 2; kk <= 256; kk <<= 1)
    for (unsigned j = kk >> 1; j > 0; j >>= 1) {
      __syncthreads();
      unsigned i = tid, ixj = i ^ j;
      if (ixj > i) {
        u64 a = k[i], b = k[ixj];
        bool desc = ((i & kk) == 0);
        if ((a < b) == desc) {
          k[i] = b; k[ixj] = a;
          int p = pay[i]; pay[i] = pay[ixj]; pay[ixj] = p;
        }
      }
    }
  __syncthreads();
  if (tid < 128) {
    int slot = pay[tid];
    int sidx = cand[img*CAND + slot];
    out[12288 + img*128 + tid] = (float)sidx;
    int base = (img*CAND + slot)*3;
    for (int j = 0; j < 3; ++j) {
      out[(img*3 + j)*128 + tid]        = c3i[base + j];
      out[6144 + (img*3 + j)*128 + tid] = c3v[base + j];
    }
  }
}

extern "C" void kernel_launch(void* const* d_in, const int* in_sizes, int n_in,
                              void* d_out, int out_size, void* d_ws, size_t ws_size,
                              hipStream_t stream) {
  const float* x     = (const float*)d_in[0];
  const float* w     = (const float*)d_in[1];
  const float* cb    = (const float*)d_in[2];
  const float* gamma = (const float*)d_in[3];
  const float* beta  = (const float*)d_in[4];
  const float* mean  = (const float*)d_in[5];
  const float* var   = (const float*)d_in[6];
  float* out = (float*)d_out;
  char*  ws  = (char*)d_ws;

  unsigned short* Bg = (unsigned short*)(ws + WS_BG);
  float* bsh  = (float*)(ws + WS_BSH);
  float* top1 = (float*)(ws + WS_TOP1);
  int*   cidx = (int*)(ws + WS_CIDX);
  u64*   ck   = (u64*)(ws + WS_CKEY);
  float* c3v = (float*)(ws + WS_C3V);
  float* c3i = (float*)(ws + WS_C3I);
  float* wT  = (float*)(ws + WS_WT);

  prep_kernel<<<COUT, 192, 0, stream>>>(w, cb, gamma, beta, mean, var, Bg, bsh, wT);
  conv_mfma_kernel<<<dim3(WW/16, HH/16, BATCH), 512, LDS_CONV, stream>>>(x, Bg, bsh, top1);
  select_kernel<<<BATCH, SNT, 0, stream>>>(top1, cidx);
  refine_kernel<<<dim3(CAND, BATCH), COUT, 0, stream>>>(x, wT, cb, gamma, beta, mean, var,
                                                        cidx, ck, c3v, c3i);
  final_kernel<<<BATCH, 256, 0, stream>>>(ck, cidx, c3v, c3i, out);
}